// Round 5
// baseline (63.899 us; speedup 1.0000x reference)
//
#include <hip/hip_runtime.h>
#include <hip/hip_bf16.h>

// RMSNorm over last dim D=2048, rows = B*S = 16384, fp32 in/out.
// out[r][d] = x[r][d] * rsqrt(mean(x[r]^2) + 5e-6) * gamma[r][d]
//
// R5: grid-stride persistent blocks + register double-buffering.
//  - 2048 blocks x 256 threads, each block processes 8 rows.
//  - Next row's x+g loads issued BEFORE current row's reduction/store:
//    the load queue never drains during the reduce/epilogue phase.
//  - sched_barrier(0) pins the prefetch above the reduction (R4 showed
//    the compiler otherwise sinks loads below it, serializing phases).
//  - Parity-indexed wsum[2][4] -> one __syncthreads per row.
//  - FETCH proven invariant at 128 MiB (L3 unsteerable, R1-R4); nt stores
//    kept for L2 hygiene.

#define D_DIM 2048
#define VEC_PER_ROW (D_DIM / 4)   // 512 float4 per row
#define EPS 5e-6f
#define ROWS_PER_BLOCK 8

typedef float f32x4 __attribute__((ext_vector_type(4)));

__global__ __launch_bounds__(256) void rmsnorm_gs_kernel(
    const float4* __restrict__ x,
    const float4* __restrict__ g,
    float4* __restrict__ out)
{
    const int t = threadIdx.x;
    const int wave = t >> 6;
    const long stride = gridDim.x;

    long row  = blockIdx.x;
    long base = row * VEC_PER_ROW;

    // Prologue: load row 0's x and gamma.
    float4 xv0 = x[base + t];
    float4 xv1 = x[base + t + 256];
    float4 gv0 = g[base + t];
    float4 gv1 = g[base + t + 256];

    __shared__ float wsum[2][4];

    #pragma unroll
    for (int i = 0; i < ROWS_PER_BLOCK; ++i) {
        // Prefetch next row's x+g while this row reduces (issue-early).
        const long nbase = base + stride * VEC_PER_ROW;
        float4 nx0, nx1, ng0, ng1;
        if (i < ROWS_PER_BLOCK - 1) {
            nx0 = x[nbase + t];
            nx1 = x[nbase + t + 256];
            ng0 = g[nbase + t];
            ng1 = g[nbase + t + 256];
        }
        // Pin the prefetch issue above the reduction (prevent sinking).
        __builtin_amdgcn_sched_barrier(0);

        float ss = xv0.x * xv0.x + xv0.y * xv0.y + xv0.z * xv0.z + xv0.w * xv0.w
                 + xv1.x * xv1.x + xv1.y * xv1.y + xv1.z * xv1.z + xv1.w * xv1.w;

        #pragma unroll
        for (int off = 32; off > 0; off >>= 1)
            ss += __shfl_down(ss, off, 64);

        if ((t & 63) == 0) wsum[i & 1][wave] = ss;
        __syncthreads();

        const float total = wsum[i & 1][0] + wsum[i & 1][1]
                          + wsum[i & 1][2] + wsum[i & 1][3];
        const float inv = rsqrtf(total * (1.0f / (float)D_DIM) + EPS);

        float4 o0, o1;
        o0.x = xv0.x * inv * gv0.x;
        o0.y = xv0.y * inv * gv0.y;
        o0.z = xv0.z * inv * gv0.z;
        o0.w = xv0.w * inv * gv0.w;
        o1.x = xv1.x * inv * gv1.x;
        o1.y = xv1.y * inv * gv1.y;
        o1.z = xv1.z * inv * gv1.z;
        o1.w = xv1.w * inv * gv1.w;
        __builtin_nontemporal_store(*(const f32x4*)&o0, (f32x4*)&out[base + t]);
        __builtin_nontemporal_store(*(const f32x4*)&o1, (f32x4*)&out[base + t + 256]);

        // Rotate the double buffer.
        xv0 = nx0; xv1 = nx1; gv0 = ng0; gv1 = ng1;
        base = nbase;
    }
}

extern "C" void kernel_launch(void* const* d_in, const int* in_sizes, int n_in,
                              void* d_out, int out_size, void* d_ws, size_t ws_size,
                              hipStream_t stream) {
    const float* x = (const float*)d_in[0];
    const float* g = (const float*)d_in[1];
    float* out = (float*)d_out;

    const int rows = out_size / D_DIM;            // 4*4096 = 16384
    const int blocks = rows / ROWS_PER_BLOCK;     // 2048
    rmsnorm_gs_kernel<<<blocks, 256, 0, stream>>>(
        (const float4*)x, (const float4*)g, (float4*)out);
}

// Round 6
// 60.509 us; speedup vs baseline: 1.0560x; 1.0560x over previous
//
#include <hip/hip_runtime.h>
#include <hip/hip_bf16.h>

// RMSNorm over last dim D=2048, rows = B*S = 16384, fp32 in/out.
// out[r][d] = x[r][d] * rsqrt(mean(x[r]^2) + 5e-6) * gamma[r][d]
//
// FINAL (revert to R2 — best measured at 59.6 us).
//
// Roofline accounting (measured, R1-R5):
//  - Compulsory traffic: read x (134 MB) + read gamma (134 MB) + write out
//    (134 MB) = 402 MB delivered per dispatch.
//  - L3 (256 MiB) serves exactly half the read set (FETCH pinned at 128 MiB
//    across plain/nt/partitioned variants -- memory-side cache, unsteerable
//    from the ISA); HBM carries 268 MB at ~4.5 TB/s.
//  - Aggregate delivered BW at 59.6 us = 6.74 TB/s, ABOVE the measured
//    6.29 TB/s pure-copy ceiling (fabric-bound, L3 hits make up the delta).
//  - Structural variants that tried to beat this (selective-nt partitioning,
//    wave-per-row barrier-free, persistent grid-stride w/ reg double-buffer)
//    landed at 61.7 / 61.9 / 63.9 us: the simple form wins.
//
// Structure: one 256-thread block per row; all 4 loads (x,g) issued up front
// (overlapped memory phases -- the R1->R2 +22% win); wave shuffle-reduce +
// 4-float LDS cross-wave combine; nt stores (writes never re-read).

#define D_DIM 2048
#define VEC_PER_ROW (D_DIM / 4)   // 512 float4 per row
#define EPS 5e-6f

typedef float f32x4 __attribute__((ext_vector_type(4)));

__global__ __launch_bounds__(256) void rmsnorm_f32_kernel(
    const float4* __restrict__ x,
    const float4* __restrict__ g,
    float4* __restrict__ out)
{
    const int t = threadIdx.x;
    const long base = (long)blockIdx.x * VEC_PER_ROW;

    // Issue ALL loads first (x and gamma) so both memory phases overlap.
    float4 xv0 = x[base + t];
    float4 xv1 = x[base + t + 256];
    float4 gv0 = g[base + t];
    float4 gv1 = g[base + t + 256];

    float ss = xv0.x * xv0.x + xv0.y * xv0.y + xv0.z * xv0.z + xv0.w * xv0.w
             + xv1.x * xv1.x + xv1.y * xv1.y + xv1.z * xv1.z + xv1.w * xv1.w;

    // Wave-64 down-shuffle reduction.
    #pragma unroll
    for (int off = 32; off > 0; off >>= 1)
        ss += __shfl_down(ss, off, 64);

    // Cross-wave (4 waves) reduction via tiny LDS scratch.
    __shared__ float wsum[4];
    const int wave = t >> 6;
    if ((t & 63) == 0) wsum[wave] = ss;
    __syncthreads();

    const float total = wsum[0] + wsum[1] + wsum[2] + wsum[3];
    const float inv = rsqrtf(total * (1.0f / (float)D_DIM) + EPS);

    float4 o0, o1;
    o0.x = xv0.x * inv * gv0.x;
    o0.y = xv0.y * inv * gv0.y;
    o0.z = xv0.z * inv * gv0.z;
    o0.w = xv0.w * inv * gv0.w;
    o1.x = xv1.x * inv * gv1.x;
    o1.y = xv1.y * inv * gv1.y;
    o1.z = xv1.z * inv * gv1.z;
    o1.w = xv1.w * inv * gv1.w;

    // Non-temporal stores (writes are never re-read).
    __builtin_nontemporal_store(*(const f32x4*)&o0, (f32x4*)&out[base + t]);
    __builtin_nontemporal_store(*(const f32x4*)&o1, (f32x4*)&out[base + t + 256]);
}

extern "C" void kernel_launch(void* const* d_in, const int* in_sizes, int n_in,
                              void* d_out, int out_size, void* d_ws, size_t ws_size,
                              hipStream_t stream) {
    const float* x = (const float*)d_in[0];
    const float* g = (const float*)d_in[1];
    float* out = (float*)d_out;

    const int rows = out_size / D_DIM;  // 4*4096 = 16384
    rmsnorm_f32_kernel<<<rows, 256, 0, stream>>>(
        (const float4*)x, (const float4*)g, (float4*)out);
}